// Round 1
// 71.097 us; speedup vs baseline: 1.1274x; 1.1274x over previous
//
#include <hip/hip_runtime.h>

#define NDIMS 3
#define H_HALF 256
#define F_DIM 16
#define PI_F 3.14159265358979323846f

typedef _Float16 half8_t __attribute__((ext_vector_type(8)));
typedef _Float16 h2 __attribute__((ext_vector_type(2)));
typedef __fp16 pk2_t __attribute__((ext_vector_type(2)));   // return type of cvt_pkrtz
typedef float float4_t __attribute__((ext_vector_type(4)));

#if __has_builtin(__builtin_amdgcn_fractf)
#define FRACT1(u) __builtin_amdgcn_fractf(u)
#else
#define FRACT1(u) ((u) - floorf(u))
#endif
// v_sin_f32/v_cos_f32 take REVOLUTIONS (sin(2*pi*u)); input pre-reduced to [0,1).
#if __has_builtin(__builtin_amdgcn_sinf)
#define SIN2PI(u) __builtin_amdgcn_sinf(u)
#define COS2PI(u) __builtin_amdgcn_cosf(u)
#else
#define SIN2PI(u) __sinf(6.283185307f * (u))
#define COS2PI(u) __cosf(6.283185307f * (u))
#endif

// pack two f32 into an f16x2 dword (v_cvt_pkrtz_f16_f32)
static __device__ __forceinline__ unsigned int pk(float lo, float hi) {
    const pk2_t p = __builtin_amdgcn_cvt_pkrtz(lo, hi);
    return __builtin_bit_cast(unsigned int, p);
}
static __device__ __forceinline__ h2 pkh(float lo, float hi) {
    const pk2_t p = __builtin_amdgcn_cvt_pkrtz(lo, hi);
    return __builtin_bit_cast(h2, p);
}

// ---------------------------------------------------------------------------
// tile_pass: one 16-row x (or t) tile against B rows for one n.
//   acc[16r x 16f] = sum_{k=0..511} A[r,k]*B[k,f],
//   k even: A=cos(2pi*(k/2+1)*v_r),  B=fr[n, 255-k/2, f]
//   k odd:  A=sin(2pi*(k/2+1)*v_r),  B=-fi[n, 255-k/2, f]
// A fragments: ONE f32 (cos,sin) base pair per lane (j = q*4+1), advanced per
// step by the constant rotation D = 2pi*16*v (4 f32 ops); the 3 sibling pairs
// derived per step in packed f16 (2 v_pk ops each). Base chain stays f32.
// ---------------------------------------------------------------------------
static __device__ __forceinline__ float4_t tile_pass(const float xq,
                                                     const unsigned int* __restrict__ Brow,
                                                     const int q) {
    // sibling-offset rotations d = 1..3 (f32-accurate, then f16-packed)
    const float u1 = FRACT1(xq);
    const float cd1 = COS2PI(u1), sd1 = SIN2PI(u1);
    const float cd2 = fmaf(cd1, cd1, -sd1 * sd1), sd2 = 2.f * sd1 * cd1;
    const float cd3 = fmaf(cd2, cd1, -sd2 * sd1), sd3 = fmaf(sd2, cd1, cd2 * sd1);
    const h2 cc1 = pkh(cd1, cd1), ns1 = pkh(-sd1, sd1);
    const h2 cc2 = pkh(cd2, cd2), ns2 = pkh(-sd2, sd2);
    const h2 cc3 = pkh(cd3, cd3), ns3 = pkh(-sd3, sd3);
    // step rotation D = 16v, base pair at j0 = q*4+1
    const float ud = FRACT1(16.f * xq);
    const float cD = COS2PI(ud), sD = SIN2PI(ud);
    const float v0 = FRACT1((float)(q * 4 + 1) * xq);
    float c0 = COS2PI(v0), s0 = SIN2PI(v0);

    float4_t acc = {0.f, 0.f, 0.f, 0.f};
    #pragma unroll
    for (int s = 0; s < 16; ++s) {
        const int4 bv = *reinterpret_cast<const int4*>(Brow + s * 16);
        const half8_t bfrag = __builtin_bit_cast(half8_t, bv);
        const h2 b0 = pkh(c0, s0);          // (c,s) of base pair
        const h2 bsw = pkh(s0, c0);         // swapped
        const h2 d1 = __builtin_elementwise_fma(bsw, ns1, b0 * cc1);
        const h2 d2 = __builtin_elementwise_fma(bsw, ns2, b0 * cc2);
        const h2 d3 = __builtin_elementwise_fma(bsw, ns3, b0 * cc3);
        const int4 av = { __builtin_bit_cast(int, b0), __builtin_bit_cast(int, d1),
                          __builtin_bit_cast(int, d2), __builtin_bit_cast(int, d3) };
        const half8_t afrag = __builtin_bit_cast(half8_t, av);
        acc = __builtin_amdgcn_mfma_f32_16x16x32_f16(afrag, bfrag, acc, 0, 0, 0);
        // advance base by D (f32 — accuracy-carrying chain)
        const float t0 = fmaf(c0, cD, -s0 * sD);
        s0 = fmaf(s0, cD, c0 * sD);
        c0 = t0;
    }
    return acc;
}

// ---------------------------------------------------------------------------
// Fully fused kernel — NO workspace use (the 256 MiB d_ws re-poison fill was
// dominating the timed region at ~2x40 us; see session notes).
// Per block:
//   1. stage B = packed f16 (fr, -fi) into LDS (48 rows x 260 dwords, padded)
//   2. waves 0..6: redundant conditionals via the SAME MFMA tile machinery,
//      with t-values (t_idx = wave*16 + row, valid < 100) in place of x;
//      trapz-weighted row sums -> shuffle reduce -> LDS red[3][7][16]
//   3. all waves: projection pass for their 16 x-rows (3 n x 16 MFMA steps)
//   4. barrier; cinv[n][f] = 1/sum_w red; epilogue product + lam-dot + store
// Block = 512 threads = 8 waves; wave owns one 16-m tile. One barrier after
// staging, one before the epilogue.
// ---------------------------------------------------------------------------
__global__ __launch_bounds__(512, 4) void main_kernel(const float* __restrict__ x,
                                                      const float* __restrict__ fr,
                                                      const float* __restrict__ fi,
                                                      const float* __restrict__ lam,
                                                      float* __restrict__ out) {
    __shared__ __align__(16) unsigned int Bls[48 * 260];   // 49920 B
    __shared__ float red[NDIMS][7][16];                    // cond partials per t-tile
    const int tid = threadIdx.x;

    // ---- prep: f32 factors -> packed f16 (cos-coef, sin-coef) dwords in LDS
    // float4 loads: 12288 floats = 3072 float4; 6 iters x 512 threads.
    {
        const float4* fr4 = (const float4*)fr;
        const float4* fi4 = (const float4*)fi;
        #pragma unroll
        for (int r = 0; r < 6; ++r) {
            const int i4 = r * 512 + tid;
            const float4 a = fr4[i4];
            const float4 b = fi4[i4];
            const int n = i4 >> 10;
            const int h = (i4 >> 2) & 255;
            const int f0 = (i4 & 3) * 4;
            const int base = (n * 16 + f0) * 260 + (255 - h);
            Bls[base      ] = pk(a.x, -b.x);
            Bls[base + 260] = pk(a.y, -b.y);
            Bls[base + 520] = pk(a.z, -b.z);
            Bls[base + 780] = pk(a.w, -b.w);
        }
    }
    __syncthreads();

    const int wave = tid >> 6;
    const int lane = tid & 63;
    const int l15 = lane & 15;     // A-row within tile; also B-col f
    const int q = lane >> 4;       // quad
    const int mbase = (blockIdx.x * 8 + wave) * 16;

    const float xv0 = x[(mbase + l15) * 3 + 0];
    const float xv1 = x[(mbase + l15) * 3 + 1];
    const float xv2 = x[(mbase + l15) * 3 + 2];
    const float lamv = lam[l15];

    // ---- conditionals pass: waves 0..6 each own one 16-row t-tile.
    // t_idx = wave*16 + row, t = 0.01 + 0.01*t_idx (trapz grid, dt = 0.01);
    // rows with t_idx >= 100 get weight 0.
    if (wave < 7) {
        const float tv = 0.01f + 0.01f * (float)(wave * 16 + l15);
        #pragma unroll
        for (int n = 0; n < 3; ++n) {
            const unsigned int* Brow = &Bls[(n * 16 + l15) * 260 + q * 4];
            const float4_t ca = tile_pass(tv, Brow, q);
            float contrib = 0.f;
            #pragma unroll
            for (int i = 0; i < 4; ++i) {
                const int ti = wave * 16 + q * 4 + i;   // C row = q*4+i
                const float y = fmaxf(fmaf(2.f, ca[i], 1.f), 0.f);
                const float w = (ti == 0 || ti == 99) ? 0.005f
                                                      : (ti < 100 ? 0.01f : 0.f);
                contrib = fmaf(w, y, contrib);
            }
            contrib += __shfl_xor(contrib, 16, 64);
            contrib += __shfl_xor(contrib, 32, 64);
            if (lane < 16) red[n][wave][lane] = contrib;  // lanes 0..15: f = lane
        }
    }

    // ---- projection pass: every wave, its 16 x-rows
    float4_t accs[3];
    #pragma unroll
    for (int n = 0; n < 3; ++n) {
        const float xq = (n == 0) ? xv0 : (n == 1 ? xv1 : xv2);
        const unsigned int* Brow = &Bls[(n * 16 + l15) * 260 + q * 4];
        accs[n] = tile_pass(xq, Brow, q);
    }

    __syncthreads();   // red[] complete

    // ---- conditionals: c = 1/trapz  (broadcast reads, same-address free)
    float cinv[3];
    #pragma unroll
    for (int n = 0; n < 3; ++n) {
        float s = 0.f;
        #pragma unroll
        for (int w = 0; w < 7; ++w) s += red[n][w][l15];
        cinv[n] = 1.f / s;
    }

    // ---- epilogue: product over n, lam-dot, 16-lane tree reduce, store
    float r0 = 1.f, r1 = 1.f, r2 = 1.f, r3 = 1.f;
    #pragma unroll
    for (int n = 0; n < 3; ++n) {
        const float cc = cinv[n];
        r0 *= fmaxf(fmaf(2.f, accs[n][0], 1.f), 0.f) * cc;
        r1 *= fmaxf(fmaf(2.f, accs[n][1], 1.f), 0.f) * cc;
        r2 *= fmaxf(fmaf(2.f, accs[n][2], 1.f), 0.f) * cc;
        r3 *= fmaxf(fmaf(2.f, accs[n][3], 1.f), 0.f) * cc;
    }
    r0 *= lamv; r1 *= lamv; r2 *= lamv; r3 *= lamv;
    #pragma unroll
    for (int off = 1; off < 16; off <<= 1) {
        r0 += __shfl_xor(r0, off, 64);
        r1 += __shfl_xor(r1, off, 64);
        r2 += __shfl_xor(r2, off, 64);
        r3 += __shfl_xor(r3, off, 64);
    }
    if (l15 == 0) {   // lanes 0,16,32,48 hold rows m = q*4 + {0..3}
        float4 o = { r0, r1, r2, r3 };
        *reinterpret_cast<float4*>(out + mbase + q * 4) = o;
    }
}

extern "C" void kernel_launch(void* const* d_in, const int* in_sizes, int n_in,
                              void* d_out, int out_size, void* d_ws, size_t ws_size,
                              hipStream_t stream) {
    const float* x   = (const float*)d_in[0];   // (M, 3)
    const float* fr  = (const float*)d_in[1];   // (3, 256, 16)
    const float* fi  = (const float*)d_in[2];   // (3, 256, 16)
    const float* lam = (const float*)d_in[3];   // (16,)
    float* out = (float*)d_out;                 // (M,)
    (void)d_ws; (void)ws_size;                  // workspace deliberately UNUSED
                                                // (avoids 256 MiB re-poison fill
                                                //  in the timed region)

    const int M = in_sizes[0] / NDIMS;

    main_kernel<<<M / 128, 512, 0, stream>>>(x, fr, fi, lam, out);
}

// Round 2
// 69.791 us; speedup vs baseline: 1.1485x; 1.0187x over previous
//
#include <hip/hip_runtime.h>

#define NDIMS 3
#define H_HALF 256
#define F_DIM 16
#define PI_F 3.14159265358979323846f

typedef _Float16 half8_t __attribute__((ext_vector_type(8)));
typedef _Float16 h2 __attribute__((ext_vector_type(2)));
typedef __fp16 pk2_t __attribute__((ext_vector_type(2)));   // return type of cvt_pkrtz
typedef float float4_t __attribute__((ext_vector_type(4)));

#if __has_builtin(__builtin_amdgcn_fractf)
#define FRACT1(u) __builtin_amdgcn_fractf(u)
#else
#define FRACT1(u) ((u) - floorf(u))
#endif
// v_sin_f32/v_cos_f32 take REVOLUTIONS (sin(2*pi*u)); input pre-reduced to [0,1).
#if __has_builtin(__builtin_amdgcn_sinf)
#define SIN2PI(u) __builtin_amdgcn_sinf(u)
#define COS2PI(u) __builtin_amdgcn_cosf(u)
#else
#define SIN2PI(u) __sinf(6.283185307f * (u))
#define COS2PI(u) __cosf(6.283185307f * (u))
#endif

// pack two f32 into an f16x2 dword (v_cvt_pkrtz_f16_f32)
static __device__ __forceinline__ unsigned int pk(float lo, float hi) {
    const pk2_t p = __builtin_amdgcn_cvt_pkrtz(lo, hi);
    return __builtin_bit_cast(unsigned int, p);
}
static __device__ __forceinline__ h2 pkh(float lo, float hi) {
    const pk2_t p = __builtin_amdgcn_cvt_pkrtz(lo, hi);
    return __builtin_bit_cast(h2, p);
}

// ---------------------------------------------------------------------------
// Rotation chain for one value v (x-sample or t-value). Generates the MFMA
// A-fragment for lane quad q at step s: 4 (cos,sin) pairs for harmonics
// j = s*16 + q*4 + {1,2,3,4}. Base pair (j0 = q*4+1) kept in f32 and advanced
// by the constant rotation D = 2pi*16*v each step; siblings d = 1..3 derived
// per step in packed f16 from f16-packed per-v constants.
// ---------------------------------------------------------------------------
struct Chain {
    float c0, s0;          // f32 accuracy-carrying base pair
    float cD, sD;          // step rotation (16*v)
    h2 cc1, ns1, cc2, ns2, cc3, ns3;   // sibling rotation constants (f16x2)
};

static __device__ __forceinline__ Chain make_chain(const float v, const int q) {
    Chain ch;
    const float u1 = FRACT1(v);
    const float cd1 = COS2PI(u1), sd1 = SIN2PI(u1);
    const float cd2 = fmaf(cd1, cd1, -sd1 * sd1), sd2 = 2.f * sd1 * cd1;
    const float cd3 = fmaf(cd2, cd1, -sd2 * sd1), sd3 = fmaf(sd2, cd1, cd2 * sd1);
    ch.cc1 = pkh(cd1, cd1); ch.ns1 = pkh(-sd1, sd1);
    ch.cc2 = pkh(cd2, cd2); ch.ns2 = pkh(-sd2, sd2);
    ch.cc3 = pkh(cd3, cd3); ch.ns3 = pkh(-sd3, sd3);
    const float ud = FRACT1(16.f * v);
    ch.cD = COS2PI(ud); ch.sD = SIN2PI(ud);
    const float v0 = FRACT1((float)(q * 4 + 1) * v);
    ch.c0 = COS2PI(v0); ch.s0 = SIN2PI(v0);
    return ch;
}

// produce afrag for current step, then advance base pair by D
static __device__ __forceinline__ half8_t step_afrag(Chain& ch) {
    const h2 b0 = pkh(ch.c0, ch.s0);          // (c,s) of base pair
    const h2 bsw = pkh(ch.s0, ch.c0);         // swapped
    const h2 d1 = __builtin_elementwise_fma(bsw, ch.ns1, b0 * ch.cc1);
    const h2 d2 = __builtin_elementwise_fma(bsw, ch.ns2, b0 * ch.cc2);
    const h2 d3 = __builtin_elementwise_fma(bsw, ch.ns3, b0 * ch.cc3);
    const int4 av = { __builtin_bit_cast(int, b0), __builtin_bit_cast(int, d1),
                      __builtin_bit_cast(int, d2), __builtin_bit_cast(int, d3) };
    const float t0 = fmaf(ch.c0, ch.cD, -ch.s0 * ch.sD);   // advance (f32 chain)
    ch.s0 = fmaf(ch.s0, ch.cD, ch.c0 * ch.sD);
    ch.c0 = t0;
    return __builtin_bit_cast(half8_t, av);
}

// ---------------------------------------------------------------------------
// Fully fused kernel, merged-pass edition.
// Key change vs round 1: cond pass and projection pass share ONE K-loop, so
//   - each ds_read_b128 of a B fragment feeds BOTH the cond MFMA and the
//     proj MFMA for that n (LDS reads halved: 96 -> 48 per heavy wave)
//   - the cond A-fragment (same t for all n) is computed ONCE per step and
//     reused for the 3 cond MFMAs (per-step A-gen VALU: 6 chains -> 4)
// Per block:
//   1. stage B = packed f16 (fr, -fi) into LDS (48 rows x 260 dwords, padded)
//   2. single K-loop, 16 steps: 3 ds_read_b128 + 4 afrags + 6 MFMA
//      (waves 0..6 run cond MFMAs; wave 7 proj-only, wave-uniform branch)
//   3. trapz-weighted cond row sums -> shuffle reduce -> LDS red[3][7][16]
//   4. barrier; cinv = 1/sum; epilogue product + lam-dot + store
// No workspace use (the 256 MiB d_ws poison fill is unconditional harness
// overhead; nothing we write can remove it).
// ---------------------------------------------------------------------------
__global__ __launch_bounds__(512, 4) void main_kernel(const float* __restrict__ x,
                                                      const float* __restrict__ fr,
                                                      const float* __restrict__ fi,
                                                      const float* __restrict__ lam,
                                                      float* __restrict__ out) {
    __shared__ __align__(16) unsigned int Bls[48 * 260];   // 49920 B
    __shared__ float red[NDIMS][7][16];                    // cond partials per t-tile
    const int tid = threadIdx.x;

    // ---- prep: f32 factors -> packed f16 (cos-coef, sin-coef) dwords in LDS
    // float4 loads: 12288 floats = 3072 float4; 6 iters x 512 threads.
    {
        const float4* fr4 = (const float4*)fr;
        const float4* fi4 = (const float4*)fi;
        #pragma unroll
        for (int r = 0; r < 6; ++r) {
            const int i4 = r * 512 + tid;
            const float4 a = fr4[i4];
            const float4 b = fi4[i4];
            const int n = i4 >> 10;
            const int h = (i4 >> 2) & 255;
            const int f0 = (i4 & 3) * 4;
            const int base = (n * 16 + f0) * 260 + (255 - h);
            Bls[base      ] = pk(a.x, -b.x);
            Bls[base + 260] = pk(a.y, -b.y);
            Bls[base + 520] = pk(a.z, -b.z);
            Bls[base + 780] = pk(a.w, -b.w);
        }
    }
    __syncthreads();

    const int wave = tid >> 6;
    const int lane = tid & 63;
    const int l15 = lane & 15;     // A-row within tile; also B-col f
    const int q = lane >> 4;       // quad
    const int mbase = (blockIdx.x * 8 + wave) * 16;
    const bool condw = (wave < 7);

    const float xv0 = x[(mbase + l15) * 3 + 0];
    const float xv1 = x[(mbase + l15) * 3 + 1];
    const float xv2 = x[(mbase + l15) * 3 + 2];
    const float lamv = lam[l15];

    // ---- chains: 3 projection (per-n x) + 1 conditionals (t, shared over n)
    Chain ch0 = make_chain(xv0, q);
    Chain ch1 = make_chain(xv1, q);
    Chain ch2 = make_chain(xv2, q);
    Chain chT;
    const float tv = 0.01f + 0.01f * (float)(wave * 16 + l15);
    if (condw) chT = make_chain(tv, q);

    const unsigned int* B0 = &Bls[(0 * 16 + l15) * 260 + q * 4];
    const unsigned int* B1 = B0 + 16 * 260;
    const unsigned int* B2 = B0 + 32 * 260;

    float4_t aP0 = {0.f, 0.f, 0.f, 0.f}, aP1 = aP0, aP2 = aP0;
    float4_t aC0 = aP0, aC1 = aP0, aC2 = aP0;

    #pragma unroll
    for (int s = 0; s < 16; ++s) {
        const int4 bv0 = *reinterpret_cast<const int4*>(B0 + s * 16);
        const int4 bv1 = *reinterpret_cast<const int4*>(B1 + s * 16);
        const int4 bv2 = *reinterpret_cast<const int4*>(B2 + s * 16);
        const half8_t bf0 = __builtin_bit_cast(half8_t, bv0);
        const half8_t bf1 = __builtin_bit_cast(half8_t, bv1);
        const half8_t bf2 = __builtin_bit_cast(half8_t, bv2);
        const half8_t af0 = step_afrag(ch0);
        aP0 = __builtin_amdgcn_mfma_f32_16x16x32_f16(af0, bf0, aP0, 0, 0, 0);
        const half8_t af1 = step_afrag(ch1);
        aP1 = __builtin_amdgcn_mfma_f32_16x16x32_f16(af1, bf1, aP1, 0, 0, 0);
        const half8_t af2 = step_afrag(ch2);
        aP2 = __builtin_amdgcn_mfma_f32_16x16x32_f16(af2, bf2, aP2, 0, 0, 0);
        if (condw) {   // wave-uniform branch: no divergence
            const half8_t afT = step_afrag(chT);
            aC0 = __builtin_amdgcn_mfma_f32_16x16x32_f16(afT, bf0, aC0, 0, 0, 0);
            aC1 = __builtin_amdgcn_mfma_f32_16x16x32_f16(afT, bf1, aC1, 0, 0, 0);
            aC2 = __builtin_amdgcn_mfma_f32_16x16x32_f16(afT, bf2, aC2, 0, 0, 0);
        }
    }

    // ---- cond partials: trapz weights over C rows (row = q*4+i, col f = l15)
    if (condw) {
        #pragma unroll
        for (int n = 0; n < 3; ++n) {
            const float4_t ca = (n == 0) ? aC0 : (n == 1 ? aC1 : aC2);
            float contrib = 0.f;
            #pragma unroll
            for (int i = 0; i < 4; ++i) {
                const int ti = wave * 16 + q * 4 + i;
                const float y = fmaxf(fmaf(2.f, ca[i], 1.f), 0.f);
                const float w = (ti == 0 || ti == 99) ? 0.005f
                                                      : (ti < 100 ? 0.01f : 0.f);
                contrib = fmaf(w, y, contrib);
            }
            contrib += __shfl_xor(contrib, 16, 64);
            contrib += __shfl_xor(contrib, 32, 64);
            if (lane < 16) red[n][wave][lane] = contrib;  // lanes 0..15: f = lane
        }
    }

    __syncthreads();   // red[] complete

    // ---- conditionals: c = 1/trapz  (broadcast reads, same-address free)
    float cinv[3];
    #pragma unroll
    for (int n = 0; n < 3; ++n) {
        float s = 0.f;
        #pragma unroll
        for (int w = 0; w < 7; ++w) s += red[n][w][l15];
        cinv[n] = 1.f / s;
    }

    // ---- epilogue: product over n, lam-dot, 16-lane tree reduce, store
    float r0 = 1.f, r1 = 1.f, r2 = 1.f, r3 = 1.f;
    #pragma unroll
    for (int n = 0; n < 3; ++n) {
        const float4_t ap = (n == 0) ? aP0 : (n == 1 ? aP1 : aP2);
        const float cc = cinv[n];
        r0 *= fmaxf(fmaf(2.f, ap[0], 1.f), 0.f) * cc;
        r1 *= fmaxf(fmaf(2.f, ap[1], 1.f), 0.f) * cc;
        r2 *= fmaxf(fmaf(2.f, ap[2], 1.f), 0.f) * cc;
        r3 *= fmaxf(fmaf(2.f, ap[3], 1.f), 0.f) * cc;
    }
    r0 *= lamv; r1 *= lamv; r2 *= lamv; r3 *= lamv;
    #pragma unroll
    for (int off = 1; off < 16; off <<= 1) {
        r0 += __shfl_xor(r0, off, 64);
        r1 += __shfl_xor(r1, off, 64);
        r2 += __shfl_xor(r2, off, 64);
        r3 += __shfl_xor(r3, off, 64);
    }
    if (l15 == 0) {   // lanes 0,16,32,48 hold rows m = q*4 + {0..3}
        float4 o = { r0, r1, r2, r3 };
        *reinterpret_cast<float4*>(out + mbase + q * 4) = o;
    }
}

extern "C" void kernel_launch(void* const* d_in, const int* in_sizes, int n_in,
                              void* d_out, int out_size, void* d_ws, size_t ws_size,
                              hipStream_t stream) {
    const float* x   = (const float*)d_in[0];   // (M, 3)
    const float* fr  = (const float*)d_in[1];   // (3, 256, 16)
    const float* fi  = (const float*)d_in[2];   // (3, 256, 16)
    const float* lam = (const float*)d_in[3];   // (16,)
    float* out = (float*)d_out;                 // (M,)
    (void)d_ws; (void)ws_size;                  // workspace unused (poison fill is
                                                // unconditional harness overhead)

    const int M = in_sizes[0] / NDIMS;

    main_kernel<<<M / 128, 512, 0, stream>>>(x, fr, fi, lam, out);
}